// Round 7
// baseline (234.566 us; speedup 1.0000x reference)
//
#include <hip/hip_runtime.h>

typedef _Float16 f16;
typedef _Float16 f16x8 __attribute__((ext_vector_type(8)));
typedef _Float16 f16x4 __attribute__((ext_vector_type(4)));
typedef float f32x4 __attribute__((ext_vector_type(4)));
typedef float f32x16 __attribute__((ext_vector_type(16)));
typedef unsigned int u32x4 __attribute__((ext_vector_type(4)));

// HEAD_DIM=64 -> 64^-0.5 = 0.125; fold log2(e) so softmax uses exp2 directly
#define SCALE_Q (0.125f * 1.44269504088896f)

__device__ __forceinline__ f32x4 mfma16x16x32(f16x8 a, f16x8 b, f32x4 c) {
  return __builtin_amdgcn_mfma_f32_16x16x32_f16(a, b, c, 0, 0, 0);
}
__device__ __forceinline__ f32x16 mfma32x32x16(f16x8 a, f16x8 b, f32x16 c) {
  return __builtin_amdgcn_mfma_f32_32x32x16_f16(a, b, c, 0, 0, 0);
}

// 2^x via v_exp_f32 (hardware transcendental)
__device__ __forceinline__ float fexp2(float x) {
  float r;
  asm("v_exp_f32 %0, %1" : "=v"(r) : "v"(x));
  return r;
}

typedef const __attribute__((address_space(1))) void* gptr1;
typedef __attribute__((address_space(3))) void* lptr3;
__device__ __forceinline__ void gload_lds16(const void* g, void* l) {
  __builtin_amdgcn_global_load_lds((gptr1)g, (lptr3)l, 16, 0, 0);
}

__device__ __forceinline__ unsigned pk2(float a, float b) {
  return __builtin_bit_cast(unsigned, __builtin_amdgcn_cvt_pkrtz(a, b));
}

// ---------------- f32 -> f16 elementwise convert (x) ----------------
__global__ __launch_bounds__(256)
void cvt_f32_f16(const float* __restrict__ in, f16* __restrict__ out, int n4) {
  int i = blockIdx.x * 256 + threadIdx.x;
  if (i >= n4) return;
  float4 v = reinterpret_cast<const float4*>(in)[i];
  f16x4 o = {(f16)v.x, (f16)v.y, (f16)v.z, (f16)v.w};
  reinterpret_cast<f16x4*>(out)[i] = o;
}

// ---------------- transpose + convert: in[R][Cin] f32 -> out[Cin][R] f16 ----------------
__global__ __launch_bounds__(256)
void transpose_cvt(const float* __restrict__ in, f16* __restrict__ out, int R, int Cin) {
  __shared__ float tile[32][33];
  int bx = blockIdx.x * 32;
  int by = blockIdx.y * 32;
  int tx = threadIdx.x & 31, ty = threadIdx.x >> 5;
#pragma unroll
  for (int i = ty; i < 32; i += 8)
    tile[i][tx] = in[(size_t)(by + i) * Cin + bx + tx];
  __syncthreads();
#pragma unroll
  for (int i = ty; i < 32; i += 8)
    out[(size_t)(bx + i) * R + by + tx] = (f16)tile[tx][i];
}

// ---------------- GEMM: C[M][N] = A[M][K] * Bt[N][K]^T, fused epilogue ----------------
template<bool QKV_EPI>
__global__ __launch_bounds__(256)
void gemm_bt(const f16* __restrict__ A, const f16* __restrict__ Bt,
             const float* __restrict__ bias, f16* __restrict__ outh,
             float* __restrict__ outf, int M, int N, int K) {
  constexpr int BM = 128, BN = 128, BK = 32;
  __shared__ f16 As[BM * BK];
  __shared__ f16 Bs[BN * BK];
  const int tid = threadIdx.x;
  const int l = tid & 63;
  const int w = tid >> 6;
  const int wr = w >> 1, wc = w & 1;
  const int bm = blockIdx.x * BM, bn = blockIdx.y * BN;
  const int l15 = l & 15, lhi = l >> 4;

  f32x4 acc[4][4] = {};

  const char* Ab = (const char*)A;
  const char* Bb = (const char*)Bt;
  const size_t rowbytes = (size_t)K * 2;

  for (int kt = 0; kt < K; kt += BK) {
    __syncthreads();
#pragma unroll
    for (int c = 0; c < 2; ++c) {
      int o = tid * 16 + c * 4096;
      int r = o >> 6;
      int cb = o & 63;
      gload_lds16(Ab + (size_t)(bm + r) * rowbytes + (size_t)kt * 2 + cb, (char*)As + o);
      gload_lds16(Bb + (size_t)(bn + r) * rowbytes + (size_t)kt * 2 + cb, (char*)Bs + o);
    }
    __syncthreads();

    f16x8 af[4], bf[4];
#pragma unroll
    for (int i = 0; i < 4; ++i)
      af[i] = *reinterpret_cast<const f16x8*>(&As[(wr * 64 + i * 16 + l15) * BK + 8 * lhi]);
#pragma unroll
    for (int i = 0; i < 4; ++i)
      bf[i] = *reinterpret_cast<const f16x8*>(&Bs[(wc * 64 + i * 16 + l15) * BK + 8 * lhi]);
#pragma unroll
    for (int i = 0; i < 4; ++i)
#pragma unroll
      for (int j = 0; j < 4; ++j)
        acc[i][j] = mfma16x16x32(af[i], bf[j], acc[i][j]);
  }

#pragma unroll
  for (int i = 0; i < 4; ++i) {
#pragma unroll
    for (int j = 0; j < 4; ++j) {
      int gr0 = bm + wr * 64 + i * 16 + 4 * lhi;
      int gc = bn + wc * 64 + j * 16 + l15;
      float b = bias[gc];
#pragma unroll
      for (int r = 0; r < 4; ++r) {
        float v = acc[i][j][r] + b;
        if constexpr (QKV_EPI) {
          if (gc < 1024) v *= SCALE_Q;
          outh[(size_t)(gr0 + r) * N + gc] = (f16)v;
        } else {
          outf[(size_t)(gr0 + r) * N + gc] = v;
        }
      }
    }
  }
}

// ---------------- flash attention v4: KV-split across wave groups ----
// qkv[4096][3072] f16: row = b*2048+t; cols [0,1024)=Q(pre-scaled incl log2e), K, V
// out: attnh[4096][1024] f16, col = h*64+d
// 512 threads = 8 waves. Waves 0-3 (grp0): keys [0,1024); waves 4-7 (grp1):
// keys [1024,2048); same 128 q-rows. Each wave: 32 q-rows (q=lane&31),
// swapped-operand 32x32 MFMA, lane-local softmax in exp2 domain. Partials
// merged through LDS (Vt reused as scratch) at the end.
__global__ __launch_bounds__(512, 4)
void attn_kernel(const f16* __restrict__ qkv, f16* __restrict__ outh) {
  constexpr int T = 2048;
  constexpr int ROW = 3072;
  __shared__ f16 Vt[2][2][64 * 64];   // [grp][buf][d][key], XOR-swizzled
  __shared__ float MlBuf[4][64][2];   // grp1 partial (m,l)

  const int tid = threadIdx.x;
  const int l = tid & 63;
  const int w = tid >> 6;          // 0..7
  const int grp = w >> 2;          // KV half
  const int wq = w & 3;            // q sub-tile
  const int l31 = l & 31, hi = l >> 5;

  // (b,h) pair in LOW bits -> one XCD serves all q-tiles of 4 pairs (L2-resident K/V)
  const int bid = blockIdx.x;
  const int p = bid & 31;
  const int b = p >> 4;
  const int h = p & 15;
  const int qt = bid >> 5;          // 0..15

  const size_t base = (size_t)b * T * ROW;
  const int q0 = qt * 128 + wq * 32;

  // Q fragments (B-operand): bq[kd] = Q[q0+l31][16kd + 8hi .. +7]  (pre-scaled)
  f16x8 bq[4];
  {
    const f16* qp = qkv + base + (size_t)(q0 + l31) * ROW + h * 64 + hi * 8;
#pragma unroll
    for (int kd = 0; kd < 4; ++kd)
      bq[kd] = *reinterpret_cast<const f16x8*>(qp + kd * 16);
  }

  const f16* Kb = qkv + base + 1024 + h * 64;
  const f16* Vb = qkv + base + 2048 + h * 64;
  const int kvbase = grp * 1024;

  f32x16 o0 = {}, o1 = {};
  float m_r = -1e30f, l_r = 0.f;

  // V staging: within a group, gid in [0,256): key gid&63, d-range 16*(gid>>6)
  const int gid = tid & 255;
  const int vt_t = gid & 63;
  const int vt_d0 = (gid >> 6) * 16;
  f16* VtG = &Vt[grp][0][0];

  f16x8 ak[2][4];   // K fragments, current tile
  f16x8 vr0, vr1;   // staged V rows for next tile

#define LOADK(KV)                                                              \
  do {                                                                         \
    _Pragma("unroll") for (int kt = 0; kt < 2; ++kt)                           \
    _Pragma("unroll") for (int kd = 0; kd < 4; ++kd)                           \
      ak[kt][kd] = *reinterpret_cast<const f16x8*>(                            \
          Kb + (size_t)((KV) + kt * 32 + l31) * ROW + kd * 16 + hi * 8);       \
  } while (0)

#define LOADV(KV)                                                              \
  do {                                                                         \
    const f16* vp = Vb + (size_t)((KV) + vt_t) * ROW + vt_d0;                  \
    vr0 = *reinterpret_cast<const f16x8*>(vp);                                 \
    vr1 = *reinterpret_cast<const f16x8*>(vp + 8);                             \
  } while (0)

#define WRITEV(DST)                                                            \
  do {                                                                         \
    _Pragma("unroll") for (int j = 0; j < 8; ++j) {                            \
      int r0 = vt_d0 + j, r1 = vt_d0 + 8 + j;                                  \
      (DST)[r0 * 64 + (vt_t ^ ((r0 & 7) << 3))] = vr0[j];                      \
      (DST)[r1 * 64 + (vt_t ^ ((r1 & 7) << 3))] = vr1[j];                      \
    }                                                                          \
  } while (0)

  LOADK(kvbase);
  LOADV(kvbase);
  WRITEV(VtG);
  __syncthreads();

  for (int t = 0; t < 16; ++t) {
    const int kv = kvbase + t * 64;
    const int nkv = (t < 15) ? kv + 64 : kv;
    f16* Vcur = VtG + (t & 1) * 4096;
    f16* Vnxt = VtG + ((t & 1) ^ 1) * 4096;

    LOADV(nkv);   // issue next V early; consumed at WRITEV below

    // S^T tiles: s_kt[r] = S[key = kv+32kt+(r&3)+8(r>>2)+4hi][q = l31] (log2 dom)
    f32x16 s0 = {}, s1 = {};
    __builtin_amdgcn_s_setprio(1);
#pragma unroll
    for (int kd = 0; kd < 4; ++kd) s0 = mfma32x32x16(ak[0][kd], bq[kd], s0);
#pragma unroll
    for (int kd = 0; kd < 4; ++kd) s1 = mfma32x32x16(ak[1][kd], bq[kd], s1);
    __builtin_amdgcn_s_setprio(0);

    LOADK(nkv);   // K regs free -> prefetch next tile

    // --- lane-local online softmax (q = l31), exp2 domain ---
    float mx[16];
#pragma unroll
    for (int r = 0; r < 16; ++r) mx[r] = fmaxf(s0[r], s1[r]);
#pragma unroll
    for (int st = 8; st > 0; st >>= 1)
#pragma unroll
      for (int r = 0; r < st; ++r) mx[r] = fmaxf(mx[r], mx[r + st]);
    float tm = fmaxf(mx[0], __shfl_xor(mx[0], 32));
    float mnew = fmaxf(m_r, tm);
    float scl = fexp2(m_r - mnew);

    float sm[16];
#pragma unroll
    for (int r = 0; r < 16; ++r) {
      s0[r] = fexp2(s0[r] - mnew);
      s1[r] = fexp2(s1[r] - mnew);
      sm[r] = s0[r] + s1[r];
    }
#pragma unroll
    for (int st = 8; st > 0; st >>= 1)
#pragma unroll
      for (int r = 0; r < st; ++r) sm[r] += sm[r + st];
    float rs = sm[0] + __shfl_xor(sm[0], 32);
    l_r = l_r * scl + rs;
    m_r = mnew;
#pragma unroll
    for (int r = 0; r < 16; ++r) { o0[r] *= scl; o1[r] *= scl; }

    // --- P^T fragments: pack pairs, exchange across lane halves via shfl_xor(32) ---
    f16x8 bp[4];
#pragma unroll
    for (int kt = 0; kt < 2; ++kt) {
#pragma unroll
      for (int s2 = 0; s2 < 2; ++s2) {
        u32x4 wd;
#pragma unroll
        for (int u = 0; u < 2; ++u) {
          float a0 = kt ? s1[8 * s2 + 2 * u] : s0[8 * s2 + 2 * u];
          float a1 = kt ? s1[8 * s2 + 2 * u + 1] : s0[8 * s2 + 2 * u + 1];
          float b0 = kt ? s1[8 * s2 + 4 + 2 * u] : s0[8 * s2 + 4 + 2 * u];
          float b1 = kt ? s1[8 * s2 + 4 + 2 * u + 1] : s0[8 * s2 + 4 + 2 * u + 1];
          unsigned wB = pk2(a0, a1);
          unsigned wA = pk2(b0, b1);
          unsigned oB = __shfl_xor(wB, 32);
          unsigned oA = __shfl_xor(wA, 32);
          wd[u]     = hi ? oA : wB;
          wd[2 + u] = hi ? wA : oB;
        }
        bp[2 * kt + s2] = __builtin_bit_cast(f16x8, wd);
      }
    }

    // --- O^T += V^T x P^T ---
    __builtin_amdgcn_s_setprio(1);
#pragma unroll
    for (int ks = 0; ks < 4; ++ks) {
      int row0 = l31;
      int c = ks * 16 + hi * 8;
      f16x8 av0 = *reinterpret_cast<const f16x8*>(&Vcur[row0 * 64 + (c ^ ((row0 & 7) << 3))]);
      o0 = mfma32x32x16(av0, bp[ks], o0);
      int row1 = 32 + l31;
      f16x8 av1 = *reinterpret_cast<const f16x8*>(&Vcur[row1 * 64 + (c ^ ((row1 & 7) << 3))]);
      o1 = mfma32x32x16(av1, bp[ks], o1);
    }
    __builtin_amdgcn_s_setprio(0);

    WRITEV(Vnxt);
    __syncthreads();
  }

  // ---- merge the two KV-half partials (grp1 -> LDS, grp0 combines+stores) ----
  __syncthreads();   // all loop reads of Vt complete; safe to reuse as f32 scratch
  float* mo = reinterpret_cast<float*>(&Vt[0][0][0]);   // 8192 f32
  const int mbase = wq * 2048 + l * 32;
  if (grp == 1) {
#pragma unroll
    for (int k = 0; k < 8; ++k) {
      int ks = k ^ (l & 7);
      f32x4 v;
      if (k < 4) { v = f32x4{o0[4*k], o0[4*k+1], o0[4*k+2], o0[4*k+3]}; }
      else       { int r = 4*(k-4); v = f32x4{o1[r], o1[r+1], o1[r+2], o1[r+3]}; }
      *reinterpret_cast<f32x4*>(&mo[mbase + ks * 4]) = v;
    }
    MlBuf[wq][l][0] = m_r;
    MlBuf[wq][l][1] = l_r;
  }
  __syncthreads();
  if (grp == 0) {
    float mb = MlBuf[wq][l][0], lb = MlBuf[wq][l][1];
    float ms = fmaxf(m_r, mb);
    float fa = fexp2(m_r - ms), fb = fexp2(mb - ms);
    float inv = 1.0f / (l_r * fa + lb * fb);
    fa *= inv; fb *= inv;
    f16* orow = outh + (size_t)(b * T + q0 + l31) * 1024 + h * 64;
#pragma unroll
    for (int k = 0; k < 8; ++k) {
      int ks = k ^ (l & 7);
      f32x4 ob = *reinterpret_cast<const f32x4*>(&mo[mbase + ks * 4]);
#pragma unroll
      for (int j = 0; j < 4; ++j) {
        int r = 4 * (k & 3) + j;
        int d = (r & 3) + 8 * (r >> 2) + 4 * hi;
        float own = (k < 4) ? o0[r] : o1[r];
        float val = own * fa + ob[j] * fb;
        orow[(k < 4 ? d : d + 32)] = (f16)val;
      }
    }
  }
#undef LOADK
#undef LOADV
#undef WRITEV
}

extern "C" void kernel_launch(void* const* d_in, const int* in_sizes, int n_in,
                              void* d_out, int out_size, void* d_ws, size_t ws_size,
                              hipStream_t stream) {
  const float* x      = (const float*)d_in[0];  // [2,2048,1024]
  const float* w_qkv  = (const float*)d_in[1];  // [1024,3072]
  const float* b_qkv  = (const float*)d_in[2];  // [3072]
  const float* w_out  = (const float*)d_in[3];  // [1024,1024]
  const float* b_out  = (const float*)d_in[4];  // [1024]
  float* out = (float*)d_out;                   // [2,2048,1024] f32

  char* ws = (char*)d_ws;
  f16* xh    = (f16*)(ws);                 //  8 MB: x as f16 [4096][1024]
  f16* wqkvT = (f16*)(ws + 8388608);       //  6 MB: w_qkv^T [3072][1024]
  f16* woutT = (f16*)(ws + 14680064);      //  2 MB: w_out^T [1024][1024]
  f16* qkvh  = (f16*)(ws + 16777216);      // 24 MB: qkv [4096][3072] (Q pre-scaled)
  f16* attnh = (f16*)(ws + 41943040);      //  8 MB: attention out [4096][1024]

  cvt_f32_f16<<<4096, 256, 0, stream>>>(x, xh, 1048576);
  transpose_cvt<<<dim3(96, 32), 256, 0, stream>>>(w_qkv, wqkvT, 1024, 3072);
  transpose_cvt<<<dim3(32, 32), 256, 0, stream>>>(w_out, woutT, 1024, 1024);
  gemm_bt<true><<<dim3(32, 24), 256, 0, stream>>>(xh, wqkvT, b_qkv, qkvh, nullptr,
                                                  4096, 3072, 1024);
  attn_kernel<<<512, 512, 0, stream>>>(qkvh, attnh);
  gemm_bt<false><<<dim3(32, 8), 256, 0, stream>>>(attnh, woutT, b_out, nullptr, out,
                                                  4096, 1024, 1024);
}

// Round 8
// 168.999 us; speedup vs baseline: 1.3880x; 1.3880x over previous
//
#include <hip/hip_runtime.h>

typedef _Float16 f16;
typedef _Float16 f16x8 __attribute__((ext_vector_type(8)));
typedef _Float16 f16x4 __attribute__((ext_vector_type(4)));
typedef float f32x4 __attribute__((ext_vector_type(4)));
typedef float f32x16 __attribute__((ext_vector_type(16)));
typedef unsigned int u32x4 __attribute__((ext_vector_type(4)));

// HEAD_DIM=64 -> 64^-0.5 = 0.125; fold log2(e) so softmax uses exp2 directly
#define SCALE_Q (0.125f * 1.44269504088896f)

__device__ __forceinline__ f32x4 mfma16x16x32(f16x8 a, f16x8 b, f32x4 c) {
  return __builtin_amdgcn_mfma_f32_16x16x32_f16(a, b, c, 0, 0, 0);
}
__device__ __forceinline__ f32x16 mfma32x32x16(f16x8 a, f16x8 b, f32x16 c) {
  return __builtin_amdgcn_mfma_f32_32x32x16_f16(a, b, c, 0, 0, 0);
}

// 2^x via v_exp_f32 (hardware transcendental)
__device__ __forceinline__ float fexp2(float x) {
  float r;
  asm("v_exp_f32 %0, %1" : "=v"(r) : "v"(x));
  return r;
}

typedef const __attribute__((address_space(1))) void* gptr1;
typedef __attribute__((address_space(3))) void* lptr3;
__device__ __forceinline__ void gload_lds16(const void* g, void* l) {
  __builtin_amdgcn_global_load_lds((gptr1)g, (lptr3)l, 16, 0, 0);
}

__device__ __forceinline__ unsigned pk2(float a, float b) {
  return __builtin_bit_cast(unsigned, __builtin_amdgcn_cvt_pkrtz(a, b));
}

// ---------------- f32 -> f16 elementwise convert (x) ----------------
__global__ __launch_bounds__(256)
void cvt_f32_f16(const float* __restrict__ in, f16* __restrict__ out, int n4) {
  int i = blockIdx.x * 256 + threadIdx.x;
  if (i >= n4) return;
  float4 v = reinterpret_cast<const float4*>(in)[i];
  f16x4 o = {(f16)v.x, (f16)v.y, (f16)v.z, (f16)v.w};
  reinterpret_cast<f16x4*>(out)[i] = o;
}

// ---------------- transpose + convert: in[R][Cin] f32 -> out[Cin][R] f16 ----------------
__global__ __launch_bounds__(256)
void transpose_cvt(const float* __restrict__ in, f16* __restrict__ out, int R, int Cin) {
  __shared__ float tile[32][33];
  int bx = blockIdx.x * 32;
  int by = blockIdx.y * 32;
  int tx = threadIdx.x & 31, ty = threadIdx.x >> 5;
#pragma unroll
  for (int i = ty; i < 32; i += 8)
    tile[i][tx] = in[(size_t)(by + i) * Cin + bx + tx];
  __syncthreads();
#pragma unroll
  for (int i = ty; i < 32; i += 8)
    out[(size_t)(bx + i) * R + by + tx] = (f16)tile[tx][i];
}

// ---------------- GEMM: C[M][N] = A[M][K] * Bt[N][K]^T, fused epilogue ----------------
template<bool QKV_EPI>
__global__ __launch_bounds__(256)
void gemm_bt(const f16* __restrict__ A, const f16* __restrict__ Bt,
             const float* __restrict__ bias, f16* __restrict__ outh,
             float* __restrict__ outf, int M, int N, int K) {
  constexpr int BM = 128, BN = 128, BK = 32;
  __shared__ f16 As[BM * BK];
  __shared__ f16 Bs[BN * BK];
  const int tid = threadIdx.x;
  const int l = tid & 63;
  const int w = tid >> 6;
  const int wr = w >> 1, wc = w & 1;
  const int bm = blockIdx.x * BM, bn = blockIdx.y * BN;
  const int l15 = l & 15, lhi = l >> 4;

  f32x4 acc[4][4] = {};

  const char* Ab = (const char*)A;
  const char* Bb = (const char*)Bt;
  const size_t rowbytes = (size_t)K * 2;

  for (int kt = 0; kt < K; kt += BK) {
    __syncthreads();
#pragma unroll
    for (int c = 0; c < 2; ++c) {
      int o = tid * 16 + c * 4096;
      int r = o >> 6;
      int cb = o & 63;
      gload_lds16(Ab + (size_t)(bm + r) * rowbytes + (size_t)kt * 2 + cb, (char*)As + o);
      gload_lds16(Bb + (size_t)(bn + r) * rowbytes + (size_t)kt * 2 + cb, (char*)Bs + o);
    }
    __syncthreads();

    f16x8 af[4], bf[4];
#pragma unroll
    for (int i = 0; i < 4; ++i)
      af[i] = *reinterpret_cast<const f16x8*>(&As[(wr * 64 + i * 16 + l15) * BK + 8 * lhi]);
#pragma unroll
    for (int i = 0; i < 4; ++i)
      bf[i] = *reinterpret_cast<const f16x8*>(&Bs[(wc * 64 + i * 16 + l15) * BK + 8 * lhi]);
#pragma unroll
    for (int i = 0; i < 4; ++i)
#pragma unroll
      for (int j = 0; j < 4; ++j)
        acc[i][j] = mfma16x16x32(af[i], bf[j], acc[i][j]);
  }

#pragma unroll
  for (int i = 0; i < 4; ++i) {
#pragma unroll
    for (int j = 0; j < 4; ++j) {
      int gr0 = bm + wr * 64 + i * 16 + 4 * lhi;
      int gc = bn + wc * 64 + j * 16 + l15;
      float b = bias[gc];
#pragma unroll
      for (int r = 0; r < 4; ++r) {
        float v = acc[i][j][r] + b;
        if constexpr (QKV_EPI) {
          if (gc < 1024) v *= SCALE_Q;
          outh[(size_t)(gr0 + r) * N + gc] = (f16)v;
        } else {
          outf[(size_t)(gr0 + r) * N + gc] = v;
        }
      }
    }
  }
}

// ---------------- flash attention v5: KV-split, register-dieted for 16 waves/CU ----
// qkv[4096][3072] f16: row = b*2048+t; cols [0,1024)=Q(pre-scaled incl log2e), K, V
// out: attnh[4096][1024] f16, col = h*64+d
// 512 threads = 8 waves. Waves 0-3 (grp0): keys [0,1024); waves 4-7 (grp1):
// keys [1024,2048); same 128 q-rows. Each wave: 32 q-rows (q=lane&31),
// swapped-operand 32x32 MFMA, lane-local softmax in exp2 domain.
// K loaded per-tile at phase start (transient regs, no cross-tile prefetch) so
// the combined VGPR+AGPR footprint fits 128/lane -> 2 blocks/CU, no spills.
__global__ __launch_bounds__(512, 4)
void attn_kernel(const f16* __restrict__ qkv, f16* __restrict__ outh) {
  constexpr int T = 2048;
  constexpr int ROW = 3072;
  __shared__ f16 Vt[2][2][64 * 64];   // [grp][buf][d][key], XOR-swizzled
  __shared__ float MlBuf[4][64][2];   // grp1 partial (m,l)

  const int tid = threadIdx.x;
  const int l = tid & 63;
  const int w = tid >> 6;          // 0..7
  const int grp = w >> 2;          // KV half
  const int wq = w & 3;            // q sub-tile
  const int l31 = l & 31, hi = l >> 5;

  // (b,h) pair in LOW bits -> one XCD serves all q-tiles of 4 pairs (L2-resident K/V)
  const int bid = blockIdx.x;
  const int p = bid & 31;
  const int b = p >> 4;
  const int h = p & 15;
  const int qt = bid >> 5;          // 0..15

  const size_t base = (size_t)b * T * ROW;
  const int q0 = qt * 128 + wq * 32;

  // Q fragments (B-operand): bq[kd] = Q[q0+l31][16kd + 8hi .. +7]  (pre-scaled)
  f16x8 bq[4];
  {
    const f16* qp = qkv + base + (size_t)(q0 + l31) * ROW + h * 64 + hi * 8;
#pragma unroll
    for (int kd = 0; kd < 4; ++kd)
      bq[kd] = *reinterpret_cast<const f16x8*>(qp + kd * 16);
  }

  const f16* Kb = qkv + base + 1024 + h * 64;
  const f16* Vb = qkv + base + 2048 + h * 64;
  const int kvbase = grp * 1024;

  f32x16 o0 = {}, o1 = {};
  float m_r = -1e30f, l_r = 0.f;

  // V staging: within a group, gid in [0,256): key gid&63, d-range 16*(gid>>6)
  const int gid = tid & 255;
  const int vt_t = gid & 63;
  const int vt_d0 = (gid >> 6) * 16;
  f16* VtG = &Vt[grp][0][0];

  f16x8 vr0, vr1;   // staged V rows for next tile

#define LOADV(KV)                                                              \
  do {                                                                         \
    const f16* vp = Vb + (size_t)((KV) + vt_t) * ROW + vt_d0;                  \
    vr0 = *reinterpret_cast<const f16x8*>(vp);                                 \
    vr1 = *reinterpret_cast<const f16x8*>(vp + 8);                             \
  } while (0)

#define WRITEV(DST)                                                            \
  do {                                                                         \
    _Pragma("unroll") for (int j = 0; j < 8; ++j) {                            \
      int r0 = vt_d0 + j, r1 = vt_d0 + 8 + j;                                  \
      (DST)[r0 * 64 + (vt_t ^ ((r0 & 7) << 3))] = vr0[j];                      \
      (DST)[r1 * 64 + (vt_t ^ ((r1 & 7) << 3))] = vr1[j];                      \
    }                                                                          \
  } while (0)

  LOADV(kvbase);
  WRITEV(VtG);
  __syncthreads();

  for (int t = 0; t < 16; ++t) {
    const int kv = kvbase + t * 64;
    const int nkv = (t < 15) ? kv + 64 : kv;
    f16* Vcur = VtG + (t & 1) * 4096;
    f16* Vnxt = VtG + ((t & 1) ^ 1) * 4096;

    // K for THIS tile: issued first so MFMA's wait leaves V loads in flight
    f16x8 ak[2][4];
#pragma unroll
    for (int kt = 0; kt < 2; ++kt)
#pragma unroll
      for (int kd = 0; kd < 4; ++kd)
        ak[kt][kd] = *reinterpret_cast<const f16x8*>(
            Kb + (size_t)(kv + kt * 32 + l31) * ROW + kd * 16 + hi * 8);

    LOADV(nkv);   // next tile's V; consumed at WRITEV below

    // S^T tiles: s_kt[r] = S[key = kv+32kt+(r&3)+8(r>>2)+4hi][q = l31] (log2 dom)
    f32x16 s0 = {}, s1 = {};
    __builtin_amdgcn_s_setprio(1);
#pragma unroll
    for (int kd = 0; kd < 4; ++kd) s0 = mfma32x32x16(ak[0][kd], bq[kd], s0);
#pragma unroll
    for (int kd = 0; kd < 4; ++kd) s1 = mfma32x32x16(ak[1][kd], bq[kd], s1);
    __builtin_amdgcn_s_setprio(0);

    // --- lane-local online softmax (q = l31), exp2 domain ---
    float mx[16];
#pragma unroll
    for (int r = 0; r < 16; ++r) mx[r] = fmaxf(s0[r], s1[r]);
#pragma unroll
    for (int st = 8; st > 0; st >>= 1)
#pragma unroll
      for (int r = 0; r < st; ++r) mx[r] = fmaxf(mx[r], mx[r + st]);
    float tm = fmaxf(mx[0], __shfl_xor(mx[0], 32));
    float mnew = fmaxf(m_r, tm);
    float scl = fexp2(m_r - mnew);

    float sm[16];
#pragma unroll
    for (int r = 0; r < 16; ++r) {
      s0[r] = fexp2(s0[r] - mnew);
      s1[r] = fexp2(s1[r] - mnew);
      sm[r] = s0[r] + s1[r];
    }
#pragma unroll
    for (int st = 8; st > 0; st >>= 1)
#pragma unroll
      for (int r = 0; r < st; ++r) sm[r] += sm[r + st];
    float rs = sm[0] + __shfl_xor(sm[0], 32);
    l_r = l_r * scl + rs;
    m_r = mnew;
#pragma unroll
    for (int r = 0; r < 16; ++r) { o0[r] *= scl; o1[r] *= scl; }

    // --- P^T fragments: pack pairs, exchange across lane halves via shfl_xor(32) ---
    f16x8 bp[4];
#pragma unroll
    for (int kt = 0; kt < 2; ++kt) {
#pragma unroll
      for (int s2 = 0; s2 < 2; ++s2) {
        u32x4 wd;
#pragma unroll
        for (int u = 0; u < 2; ++u) {
          float a0 = kt ? s1[8 * s2 + 2 * u] : s0[8 * s2 + 2 * u];
          float a1 = kt ? s1[8 * s2 + 2 * u + 1] : s0[8 * s2 + 2 * u + 1];
          float b0 = kt ? s1[8 * s2 + 4 + 2 * u] : s0[8 * s2 + 4 + 2 * u];
          float b1 = kt ? s1[8 * s2 + 4 + 2 * u + 1] : s0[8 * s2 + 4 + 2 * u + 1];
          unsigned wB = pk2(a0, a1);
          unsigned wA = pk2(b0, b1);
          unsigned oB = __shfl_xor(wB, 32);
          unsigned oA = __shfl_xor(wA, 32);
          wd[u]     = hi ? oA : wB;
          wd[2 + u] = hi ? wA : oB;
        }
        bp[2 * kt + s2] = __builtin_bit_cast(f16x8, wd);
      }
    }

    // --- O^T += V^T x P^T ---
    __builtin_amdgcn_s_setprio(1);
#pragma unroll
    for (int ks = 0; ks < 4; ++ks) {
      int row0 = l31;
      int c = ks * 16 + hi * 8;
      f16x8 av0 = *reinterpret_cast<const f16x8*>(&Vcur[row0 * 64 + (c ^ ((row0 & 7) << 3))]);
      o0 = mfma32x32x16(av0, bp[ks], o0);
      int row1 = 32 + l31;
      f16x8 av1 = *reinterpret_cast<const f16x8*>(&Vcur[row1 * 64 + (c ^ ((row1 & 7) << 3))]);
      o1 = mfma32x32x16(av1, bp[ks], o1);
    }
    __builtin_amdgcn_s_setprio(0);

    WRITEV(Vnxt);
    __syncthreads();
  }

  // ---- merge the two KV-half partials (grp1 -> LDS, grp0 combines+stores) ----
  __syncthreads();   // all loop reads of Vt complete; safe to reuse as f32 scratch
  float* mo = reinterpret_cast<float*>(&Vt[0][0][0]);   // 8192 f32
  const int mbase = wq * 2048 + l * 32;
  if (grp == 1) {
#pragma unroll
    for (int k = 0; k < 8; ++k) {
      int ks = k ^ (l & 7);
      f32x4 v;
      if (k < 4) { v = f32x4{o0[4*k], o0[4*k+1], o0[4*k+2], o0[4*k+3]}; }
      else       { int r = 4*(k-4); v = f32x4{o1[r], o1[r+1], o1[r+2], o1[r+3]}; }
      *reinterpret_cast<f32x4*>(&mo[mbase + ks * 4]) = v;
    }
    MlBuf[wq][l][0] = m_r;
    MlBuf[wq][l][1] = l_r;
  }
  __syncthreads();
  if (grp == 0) {
    float mb = MlBuf[wq][l][0], lb = MlBuf[wq][l][1];
    float ms = fmaxf(m_r, mb);
    float fa = fexp2(m_r - ms), fb = fexp2(mb - ms);
    float inv = 1.0f / (l_r * fa + lb * fb);
    fa *= inv; fb *= inv;
    f16* orow = outh + (size_t)(b * T + q0 + l31) * 1024 + h * 64;
#pragma unroll
    for (int k = 0; k < 8; ++k) {
      int ks = k ^ (l & 7);
      f32x4 ob = *reinterpret_cast<const f32x4*>(&mo[mbase + ks * 4]);
#pragma unroll
      for (int j = 0; j < 4; ++j) {
        int r = 4 * (k & 3) + j;
        int d = (r & 3) + 8 * (r >> 2) + 4 * hi;
        float own = (k < 4) ? o0[r] : o1[r];
        float val = own * fa + ob[j] * fb;
        orow[(k < 4 ? d : d + 32)] = (f16)val;
      }
    }
  }
#undef LOADV
#undef WRITEV
}

extern "C" void kernel_launch(void* const* d_in, const int* in_sizes, int n_in,
                              void* d_out, int out_size, void* d_ws, size_t ws_size,
                              hipStream_t stream) {
  const float* x      = (const float*)d_in[0];  // [2,2048,1024]
  const float* w_qkv  = (const float*)d_in[1];  // [1024,3072]
  const float* b_qkv  = (const float*)d_in[2];  // [3072]
  const float* w_out  = (const float*)d_in[3];  // [1024,1024]
  const float* b_out  = (const float*)d_in[4];  // [1024]
  float* out = (float*)d_out;                   // [2,2048,1024] f32

  char* ws = (char*)d_ws;
  f16* xh    = (f16*)(ws);                 //  8 MB: x as f16 [4096][1024]
  f16* wqkvT = (f16*)(ws + 8388608);       //  6 MB: w_qkv^T [3072][1024]
  f16* woutT = (f16*)(ws + 14680064);      //  2 MB: w_out^T [1024][1024]
  f16* qkvh  = (f16*)(ws + 16777216);      // 24 MB: qkv [4096][3072] (Q pre-scaled)
  f16* attnh = (f16*)(ws + 41943040);      //  8 MB: attention out [4096][1024]

  cvt_f32_f16<<<4096, 256, 0, stream>>>(x, xh, 1048576);
  transpose_cvt<<<dim3(96, 32), 256, 0, stream>>>(w_qkv, wqkvT, 1024, 3072);
  transpose_cvt<<<dim3(32, 32), 256, 0, stream>>>(w_out, woutT, 1024, 1024);
  gemm_bt<true><<<dim3(32, 24), 256, 0, stream>>>(xh, wqkvT, b_qkv, qkvh, nullptr,
                                                  4096, 3072, 1024);
  attn_kernel<<<512, 512, 0, stream>>>(qkvh, attnh);
  gemm_bt<false><<<dim3(32, 8), 256, 0, stream>>>(attnh, woutT, b_out, nullptr, out,
                                                  4096, 1024, 1024);
}